// Round 6
// baseline (1242.370 us; speedup 1.0000x reference)
//
#include <hip/hip_runtime.h>

#define CIN 64
#define COUT 64
#define BATCH 32
#define KTOT 576            // CIN * 9
#define NPOS 1024

// halo-padded transposed input: xT[i][34][34][b]
__device__ float g_xT[CIN * 34 * 34 * BATCH];

// Coalesced transpose repack: one block per (i, hh). Reads x rows (lanes over
// w, 128 B segments), transposes through LDS, writes g_xT rows (lanes over b,
// 128 B segments). Halo rows/cols written as zeros.
__global__ __launch_bounds__(256) void repack_kernel(const float* __restrict__ x) {
    __shared__ float tile[32 * 33];        // [b][w], pad 33 -> conflict-free
    const int i   = blockIdx.x;            // 0..63
    const int hh  = blockIdx.y;            // 0..33
    const int tid = threadIdx.x;

    float* dst = &g_xT[((i * 34 + hh) * 34) * BATCH];

    if (hh == 0 || hh == 33) {             // halo row: all zeros (34*32 floats)
        for (int idx = tid; idx < 34 * BATCH; idx += 256) dst[idx] = 0.f;
        return;
    }
    const int hs = hh - 1;
#pragma unroll
    for (int bb = 0; bb < 4; ++bb) {       // read 8 b-rows per pass
        int b = bb * 8 + (tid >> 5);
        int w = tid & 31;
        tile[b * 33 + w] = x[(b << 16) + (i << 10) + (hs << 5) + w];
    }
    __syncthreads();
#pragma unroll
    for (int q = 0; q < 5; ++q) {          // write 8 ww-rows per pass (34 total)
        int ww = q * 8 + (tid >> 5);
        if (ww < 34) {
            int b = tid & 31;
            float v = (ww == 0 || ww == 33) ? 0.f : tile[b * 33 + (ww - 1)];
            dst[ww * BATCH + b] = v;
        }
    }
}

// Pure register-streaming kernel: NO LDS in the main loop (rounds 0-5 showed
// every staged variant pins at ~1.6 TB/s effective W-stream = MLP-limited).
// Block = (position p, cout-half oh), grid 2048, 128 threads = 2 waves.
// Wave wv: K in [wv*288, wv*288+288) for its 32 couts x 32 batch.
// Lane: o = oc*8 + (l>>3), b = (l&7)*4 + bb -> acc[4][4].
//   W: 4 contiguous per-lane row streams, base + imm offsets (g<<4 B <= 272).
//      8 og2-lanes = 8 rows (lines reused 4x over g), bg-lanes broadcast.
//   P: direct from L2 (g_xT slice L2-resident); 8 bg-lanes = 128 B line.
// Hand 2-deep A/B register pipeline (64 VGPR buffers) forces >=2 g-iters of
// loads in flight; compiler hoists more up to the 128-VGPR cap.
__global__ __launch_bounds__(128, 4) void local2d_kernel(
    const float* __restrict__ weight,
    const float* __restrict__ bias,
    float* __restrict__ out)
{
    __shared__ __align__(16) float R[32 * 36];   // 4.6 KB epilogue scratch

    const int wv  = threadIdx.x >> 6;      // wave 0/1 (K-half)
    const int l   = threadIdx.x & 63;
    const int bg  = l & 7;                 // b-group: b = bg*4 + bb
    const int og2 = l >> 3;                // o-sub:   o = oc*8 + og2

    // row-granular XCD swizzle (r4/r5 proven mapping)
    int bid = blockIdx.x;
    int xcd = bid & 7;
    int t   = bid >> 3;                    // 0..255
    int oh  = t & 1;                       // cout half
    int tt  = t >> 1;                      // 0..127
    int y   = ((tt >> 5) << 3) | xcd;
    int xw  = tt & 31;
    int p   = (y << 5) | xw;               // position

    const int kbase = wv * 288;
    const float* wr0 = weight + ((long)p * COUT + (oh << 5) + og2) * KTOT + kbase;
    const float* pb0 = g_xT + ((((wv << 5) * 1156) + y * 34 + xw) << 5) + (bg << 2);

    float acc[4][4];
#pragma unroll
    for (int a = 0; a < 4; ++a)
#pragma unroll
        for (int c = 0; c < 4; ++c) acc[a][c] = 0.f;

    float4 wA[4], pA[4], wB[4], pB[4];

    // g = k-quad index within the super-iter (compile-time under unroll)
    auto ldW = [&](const float* wr, int g, float4 (&w)[4]) {
#pragma unroll
        for (int oc = 0; oc < 4; ++oc)
            w[oc] = *(const float4*)(wr + oc * (8 * KTOT) + (g << 2));
    };
    auto ldP = [&](const float* pb, int g, float4 (&pr)[4]) {
#pragma unroll
        for (int j = 0; j < 4; ++j) {
            const int c  = (g << 2) + j;   // 0..71, compile-time
            const int di = c / 9;
            const int rr = c - 9 * di;
            const int kh = rr / 3;
            const int kw = rr - 3 * kh;
            pr[j] = *(const float4*)(pb + ((di * 1156 + kh * 34 + kw) << 5));
        }
    };
    auto fmab = [&](const float4 (&w)[4], const float4 (&pr)[4]) {
        const float* prf = (const float*)pr;
#pragma unroll
        for (int oc = 0; oc < 4; ++oc)
#pragma unroll
            for (int bb = 0; bb < 4; ++bb) {
                float a = acc[oc][bb];
                a = fmaf(w[oc].x, prf[0 + bb],  a);
                a = fmaf(w[oc].y, prf[4 + bb],  a);
                a = fmaf(w[oc].z, prf[8 + bb],  a);
                a = fmaf(w[oc].w, prf[12 + bb], a);
                acc[oc][bb] = a;
            }
    };

    // 4 super-iters x 18 k-quads (72 k = 8 i-planes each); P offsets repeat
    // per super-iter (lcm(4,9)=36 k), so inner offsets stay compile-time.
    const float* wr = wr0;
    const float* pb = pb0;
    ldW(wr, 0, wA); ldP(pb, 0, pA);
    for (int dq = 0; dq < 4; ++dq) {
        const float* wrn = wr + 72;                    // next super-iter bases
        const float* pbn = pb + ((8 * 1156) << 5);
#pragma unroll
        for (int h = 0; h < 9; ++h) {
            ldW(wr, 2 * h + 1, wB); ldP(pb, 2 * h + 1, pB);
            fmab(wA, pA);
            if (h < 8) {
                ldW(wr, 2 * h + 2, wA); ldP(pb, 2 * h + 2, pA);
            } else if (dq < 3) {
                ldW(wrn, 0, wA); ldP(pbn, 0, pA);      // cross-boundary prefetch
            }
            fmab(wB, pB);
        }
        wr = wrn;
        pb = pbn;
    }

    // ---- cross-wave reduction: wave1 dumps partials, wave0 sums + stores ----
    if (wv == 1) {
#pragma unroll
        for (int oc = 0; oc < 4; ++oc) {
            int o = (oc << 3) + og2;
            *(float4*)(&R[o * 36 + (bg << 2)]) =
                make_float4(acc[oc][0], acc[oc][1], acc[oc][2], acc[oc][3]);
        }
    }
    __syncthreads();
    if (wv == 0) {
#pragma unroll
        for (int oc = 0; oc < 4; ++oc) {
            int o  = (oc << 3) + og2;
            int of = (oh << 5) + o;        // global cout
            float4 r = *(const float4*)(&R[o * 36 + (bg << 2)]);
            float bv = bias[(of << 10) + p];
            int b0 = bg << 2;
            out[((b0 + 0) << 16) + (of << 10) + p] = acc[oc][0] + r.x + bv;
            out[((b0 + 1) << 16) + (of << 10) + p] = acc[oc][1] + r.y + bv;
            out[((b0 + 2) << 16) + (of << 10) + p] = acc[oc][2] + r.z + bv;
            out[((b0 + 3) << 16) + (of << 10) + p] = acc[oc][3] + r.w + bv;
        }
    }
}

extern "C" void kernel_launch(void* const* d_in, const int* in_sizes, int n_in,
                              void* d_out, int out_size, void* d_ws, size_t ws_size,
                              hipStream_t stream) {
    const float* x      = (const float*)d_in[0];
    const float* weight = (const float*)d_in[1];
    const float* bias   = (const float*)d_in[2];
    float* out          = (float*)d_out;

    hipLaunchKernelGGL(repack_kernel, dim3(CIN, 34), dim3(256), 0, stream, x);
    hipLaunchKernelGGL(local2d_kernel, dim3(2 * NPOS), dim3(128), 0, stream,
                       weight, bias, out);
}

// Round 7
// 249.640 us; speedup vs baseline: 4.9767x; 4.9767x over previous
//
#include <hip/hip_runtime.h>

#define CIN 64
#define COUT 64
#define BATCH 32
#define KTOT 576            // CIN * 9
#define NPOS 1024
#define KC 32               // k-chunk per wave-iteration (full 128-B W rows)
#define KHALF 288           // K per wave (2-way K-split)
#define NCW 9               // chunks per wave = 288/32

// halo-padded transposed input: xT[i][34][34][b]
__device__ float g_xT[CIN * 34 * 34 * BATCH];

// Coalesced transpose repack: one block per (i, hh). Reads x rows (lanes over
// w, 128 B segments), transposes through LDS, writes g_xT rows (lanes over b,
// 128 B segments). Halo rows/cols written as zeros.
__global__ __launch_bounds__(256) void repack_kernel(const float* __restrict__ x) {
    __shared__ float tile[32 * 33];        // [b][w], pad 33 -> conflict-free
    const int i   = blockIdx.x;            // 0..63
    const int hh  = blockIdx.y;            // 0..33
    const int tid = threadIdx.x;

    float* dst = &g_xT[((i * 34 + hh) * 34) * BATCH];

    if (hh == 0 || hh == 33) {             // halo row: all zeros (34*32 floats)
        for (int idx = tid; idx < 34 * BATCH; idx += 256) dst[idx] = 0.f;
        return;
    }
    const int hs = hh - 1;
#pragma unroll
    for (int bb = 0; bb < 4; ++bb) {       // read 8 b-rows per pass
        int b = bb * 8 + (tid >> 5);
        int w = tid & 31;
        tile[b * 33 + w] = x[(b << 16) + (i << 10) + (hs << 5) + w];
    }
    __syncthreads();
#pragma unroll
    for (int q = 0; q < 5; ++q) {          // write 8 ww-rows per pass (34 total)
        int ww = q * 8 + (tid >> 5);
        if (ww < 34) {
            int b = tid & 31;
            float v = (ww == 0 || ww == 33) ? 0.f : tile[b * 33 + (ww - 1)];
            dst[ww * BATCH + b] = v;
        }
    }
}

__device__ __forceinline__ void async16(const void* src, void* dst_lds) {
    __builtin_amdgcn_global_load_lds(
        (const __attribute__((address_space(1))) void*)src,
        (__attribute__((address_space(3))) void*)dst_lds,
        16, 0, 0);
}

// Grid 2048 = (position p) x (cout-half oh); 128 threads = 2 waves; wave wv
// computes K in [wv*288, wv*288+288) for its 32 couts x 32 batch.
// r4 loop skeleton (spill-free), KC=32: every DMA fetches FULLY-USED 128-B
// lines (rounds 0-6 showed the wall is per-CU line-request throughput at
// ~6 cyc/line; r0/r4 W-DMAs used only 64/32 B per line = 2-4x line overhead).
//   W chunk: 32 o x 32 k = 4 KB = 4 DMAs; DMA g covers o-rows [8g,8g+8):
//     lane l -> row g*8+(l&7), k-quad l>>3 -> per row 8 lanes read 128 B
//     contiguous, 128-B aligned (KTOT*4=2304=18*128, kbase*4=1152=9*128).
//     LDS granule (16 B): g*64 + kq*8 + og -> compute reads 8 consecutive
//     granules per (oc,kq) = all 32 banks, compile-time offsets.
//   P chunk: 32 k x 32 b = 4 KB = 4 DMAs, each 8 k-rows of 128 B (unchanged).
// 3-deep pipeline; 8 DMAs/chunk -> vmcnt(8) = chunk c landed, c+1 in flight.
__global__ __launch_bounds__(128, 2) void local2d_kernel(
    const float* __restrict__ weight,
    const float* __restrict__ bias,
    float* __restrict__ out)
{
    // per-wave private staging: [wave][buf][...]
    __shared__ float Wl[2][3][32 * KC];    // 32 o x 32 k, granule-permuted
    __shared__ float Pl[2][3][KC * BATCH]; // 32 k x 32 b

    const int wv = threadIdx.x >> 6;       // wave id 0/1
    const int l  = threadIdx.x & 63;       // lane

    const int og = l & 7, bg = l >> 3;     // compute roles: o-sub, b-quad

    // XCD swizzle (r4 proven): xcd owns whole output rows; the two oh-halves
    // of a position are dispatch-adjacent -> g_xT L2 reuse.
    int bid = blockIdx.x;
    int xcd = bid & 7;
    int t   = bid >> 3;                    // 0..255
    int oh  = t & 1;                       // cout half
    int tt  = t >> 1;                      // 0..127
    int y   = ((tt >> 5) << 3) | xcd;
    int xw  = tt & 31;
    int p   = (y << 5) | xw;               // position = y*32 + x

    const int kbase = wv * KHALF;
    const float* wpos = weight + ((long)p * COUT + (oh << 5)) * KTOT;
    // W DMA lane role: row (l&7) within 8-row group, k-quad (l>>3)
    const float* wsrc0 = wpos + (l & 7) * KTOT + ((l >> 3) << 2) + kbase;

    float acc[4][4];
#pragma unroll
    for (int a = 0; a < 4; ++a)
#pragma unroll
        for (int c = 0; c < 4; ++c) acc[a][c] = 0.f;

    auto stage = [&](int c, int bsel) {
        const float* ws = wsrc0 + c * KC;
        // W chunk: DMA g covers o-rows [8g, 8g+8), 128 B/row, fully used
#pragma unroll
        for (int g = 0; g < 4; ++g)
            async16(ws + g * (8 * KTOT), &Wl[wv][bsel][g << 8]);
        // P chunk: DMA q covers 8 k-rows x 128 B contig each
#pragma unroll
        for (int q = 0; q < 4; ++q) {
            int k  = kbase + c * KC + (q << 3) + (l >> 3);
            int i  = k / 9;
            int r  = k - i * 9;
            int kh = r / 3;
            int kw = r - kh * 3;
            const float* ps =
                &g_xT[(((i * 34) + y + kh) * 34 + xw + kw) * BATCH + ((l & 7) << 2)];
            async16(ps, &Pl[wv][bsel][q << 8]);
        }
    };

    auto compute = [&](int bsel) {
        const float* Wb = &Wl[wv][bsel][og << 2];
        const float* Pb = &Pl[wv][bsel][bg << 2];
#pragma unroll
        for (int kk = 0; kk < KC; kk += 4) {
            float4 pr[4];
#pragma unroll
            for (int j = 0; j < 4; ++j)
                pr[j] = *(const float4*)(Pb + (kk + j) * BATCH);
            const float* prf = (const float*)pr;
#pragma unroll
            for (int oc = 0; oc < 4; ++oc) {
                // granule (g=oc, kq=kk>>2, og): float offset oc*256 + kq*32 + og*4
                float4 wr = *(const float4*)(Wb + (oc << 8) + (kk << 3));
#pragma unroll
                for (int bb = 0; bb < 4; ++bb) {
                    float a = acc[oc][bb];
                    a = fmaf(wr.x, prf[0 * 4 + bb], a);
                    a = fmaf(wr.y, prf[1 * 4 + bb], a);
                    a = fmaf(wr.z, prf[2 * 4 + bb], a);
                    a = fmaf(wr.w, prf[3 * 4 + bb], a);
                    acc[oc][bb] = a;
                }
            }
        }
    };

    stage(0, 0);
    stage(1, 1);
    for (int c = 0; c < NCW - 1; ++c) {
        // chunk c's 8 DMAs are the oldest; <=8 left => chunk c landed,
        // chunk c+1 still in flight across this compute phase.
        asm volatile("s_waitcnt vmcnt(8)" ::: "memory");
        // WAR guard: reads of buf (c+2)%3 were issued in compute(c-1), long
        // retired -> this drain is ~free but guarantees sampling order.
        asm volatile("s_waitcnt lgkmcnt(0)" ::: "memory");
        if (c + 2 < NCW) stage(c + 2, (c + 2) % 3);
        compute(c % 3);
    }
    asm volatile("s_waitcnt vmcnt(0)" ::: "memory");
    compute((NCW - 1) % 3);

    // ---- cross-wave reduction: wave1 dumps partials, wave0 sums + stores ----
    __syncthreads();                       // both waves done with staging bufs
    float* R = &Wl[0][0][0];               // 32 o x 32 b, stride 36 (1152 floats)
    if (wv == 1) {
#pragma unroll
        for (int oc = 0; oc < 4; ++oc) {
            int o = (oc << 3) + og;
            *(float4*)(&R[o * 36 + (bg << 2)]) =
                make_float4(acc[oc][0], acc[oc][1], acc[oc][2], acc[oc][3]);
        }
    }
    __syncthreads();
    if (wv == 0) {
#pragma unroll
        for (int oc = 0; oc < 4; ++oc) {
            int o  = (oc << 3) + og;
            int of = (oh << 5) + o;        // global cout
            float bv = bias[(of << 10) + p];
            float4 r = *(const float4*)(&R[o * 36 + (bg << 2)]);
            const float* rf = (const float*)&r;
#pragma unroll
            for (int bb = 0; bb < 4; ++bb) {
                int b = (bg << 2) + bb;
                out[(b << 16) + (of << 10) + p] = acc[oc][bb] + rf[bb] + bv;
            }
        }
    }
}

extern "C" void kernel_launch(void* const* d_in, const int* in_sizes, int n_in,
                              void* d_out, int out_size, void* d_ws, size_t ws_size,
                              hipStream_t stream) {
    const float* x      = (const float*)d_in[0];
    const float* weight = (const float*)d_in[1];
    const float* bias   = (const float*)d_in[2];
    float* out          = (float*)d_out;

    hipLaunchKernelGGL(repack_kernel, dim3(CIN, 34), dim3(256), 0, stream, x);
    hipLaunchKernelGGL(local2d_kernel, dim3(2 * NPOS), dim3(128), 0, stream,
                       weight, bias, out);
}